// Round 11
// baseline (98.152 us; speedup 1.0000x reference)
//
#include <hip/hip_runtime.h>
#include <hip/hip_bf16.h>

// SimCLR NT-Xent loss. B=4096, D=256, N=2B=8192 rows.
// loss = (1/N) sum_i [ log(denom_i) - log(pos_i) ]
//   denom_i = sum_{j!=i} exp(2*sim_ij),  pos_i = cos(z_i, z_{i+-B}) (fp32 path)
//
// R11: prefetch-pipelined denom. Block = (bi, 4-tile bj chunk); A staged to
// LDS once -> A-frags in registers for the whole chunk; B double-buffered
// (2 x 16 KB), ONE barrier per 64-row stage with the next stage's
// global_load_lds issued right after the barrier and drained a full compute
// phase later (AITER-style pipeline; fixes the R7/R10 barrier-drain stall).
// Row-sums accumulate in regs across the chunk; epilogue once per block.
// fp8 e4m3 scaled-MFMA datapath + XOR-swizzle verified (absmax 0.0, R6-R10).

#define NROWS 8192
#define BHALF 4096
#define DDIM  256
#define CHUNK 4

typedef __attribute__((ext_vector_type(4))) int   i32x4;
typedef __attribute__((ext_vector_type(8))) int   i32x8;
typedef __attribute__((ext_vector_type(4))) float f32x4;

#define SCALE1 0x7F7F7F7F               // e8m0 biased-127 = 2^0 in every byte
#define TWO_LOG2E 2.8853900817779268f   // 2/ln(2): exp(2x) = exp2(x*TWO_LOG2E)

__device__ __forceinline__ void load_lds16(const unsigned char* g, unsigned char* l) {
    __builtin_amdgcn_global_load_lds(
        (const __attribute__((address_space(1))) void*)g,
        (__attribute__((address_space(3))) void*)l, 16, 0, 0);
}

// Kernel 1: norms + fp8-normalized matrix + positive-pair log partials +
// denom zero-init + out zero-init. (unchanged, verified)
__global__ __launch_bounds__(256) void prep_kernel(const float* __restrict__ z1,
                                                   const float* __restrict__ z2,
                                                   unsigned char* __restrict__ zn8,
                                                   float* __restrict__ posPart,
                                                   float* __restrict__ denom,
                                                   float* __restrict__ out) {
    __shared__ float sp[4];
    int wave = threadIdx.x >> 6;
    int lane = threadIdx.x & 63;
    int i    = blockIdx.x * 4 + wave;
    float4 a = reinterpret_cast<const float4*>(z1 + (size_t)i * DDIM)[lane];
    float4 b = reinterpret_cast<const float4*>(z2 + (size_t)i * DDIM)[lane];
    float ss1 = a.x * a.x + a.y * a.y + a.z * a.z + a.w * a.w;
    float ss2 = b.x * b.x + b.y * b.y + b.z * b.z + b.w * b.w;
    float dd  = a.x * b.x + a.y * b.y + a.z * b.z + a.w * b.w;
    #pragma unroll
    for (int off = 32; off; off >>= 1) {
        ss1 += __shfl_xor(ss1, off);
        ss2 += __shfl_xor(ss2, off);
        dd  += __shfl_xor(dd, off);
    }
    float n1 = fmaxf(sqrtf(ss1), 1e-8f);
    float n2 = fmaxf(sqrtf(ss2), 1e-8f);
    float i1 = 1.0f / n1, i2 = 1.0f / n2;
    int pa = __builtin_amdgcn_cvt_pk_fp8_f32(a.x * i1, a.y * i1, 0, 0);
    pa     = __builtin_amdgcn_cvt_pk_fp8_f32(a.z * i1, a.w * i1, pa, 1);
    int pb = __builtin_amdgcn_cvt_pk_fp8_f32(b.x * i2, b.y * i2, 0, 0);
    pb     = __builtin_amdgcn_cvt_pk_fp8_f32(b.z * i2, b.w * i2, pb, 1);
    reinterpret_cast<int*>(zn8 + (size_t)i * DDIM)[lane] = pa;
    reinterpret_cast<int*>(zn8 + (size_t)(i + BHALF) * DDIM)[lane] = pb;
    if (lane == 0) sp[wave] = __logf(dd * i1 * i2);
    if (threadIdx.x < 8) denom[blockIdx.x * 8 + threadIdx.x] = 0.0f;
    if (blockIdx.x == 0 && threadIdx.x == 64) out[0] = 0.0f;
    __syncthreads();
    if (threadIdx.x == 0)
        posPart[blockIdx.x] = sp[0] + sp[1] + sp[2] + sp[3];
}

// Kernel 2: fp8 MFMA sim-GEMM + exp row/col-sums, triangular (bi, bj-chunk)
// blocks, B prefetch-pipelined through 2 x 16 KB LDS buffers.
__global__ __launch_bounds__(256, 2) void denom_kernel(const unsigned char* __restrict__ zn8,
                                                       float* __restrict__ denom) {
    __shared__ __align__(16) unsigned char sA[128 * DDIM];      // 32 KB
    __shared__ __align__(16) unsigned char sB[2][64 * DDIM];    // 2 x 16 KB

    int bi  = blockIdx.y;                 // 0..63
    int bj0 = bi + blockIdx.x * CHUNK;    // chunk start
    if (bj0 > 63) return;                 // empty block (uniform exit, pre-LDS)
    int bjEnd = min(bj0 + CHUNK, 64);
    int S = 2 * (bjEnd - bj0);            // 64-row stages
    int iBase = bi * 128;

    int t    = threadIdx.x;
    int lane = t & 63;
    int wave = t >> 6;
    int col  = lane & 15;
    int quad = lane >> 4;
    int wm = wave >> 1, wn = wave & 1;

    // staging addresses (granule id = q*256 + t; row = q*16 + rowL;
    // slot pos (t&15) holds k-chunk (t&15)^rowL — verified XOR swizzle)
    int rowL  = t >> 4;
    int chunk = (t & 15) ^ rowL;

    // ---- prologue: stage A (full 128 x 256) + B stage 0 ----
    {
        const unsigned char* gA = zn8 + (size_t)(iBase + rowL) * DDIM + chunk * 16;
        unsigned char* lA = sA + t * 16;
        #pragma unroll
        for (int q = 0; q < 8; q++)
            load_lds16(gA + q * 4096, lA + q * 4096);
        const unsigned char* gB = zn8 + (size_t)(bj0 * 128 + rowL) * DDIM + chunk * 16;
        unsigned char* lB = sB[0] + t * 16;
        #pragma unroll
        for (int q = 0; q < 4; q++)
            load_lds16(gB + q * 4096, lB + q * 4096);
    }

    i32x8 af[4][2];                        // A-frags, register-resident all chunk
    float rs[4][4];                        // row-sums, accumulated all chunk
    #pragma unroll
    for (int mt = 0; mt < 4; mt++)
        #pragma unroll
        for (int r = 0; r < 4; r++) rs[mt][r] = 0.f;

    const unsigned char* aRow = sA + (size_t)(wm * 64 + col) * DDIM;

    for (int s = 0; s < S; s++) {
        __syncthreads();   // drains stage s (in flight since iter s-1) + prev reads

        // prefetch stage s+1 into the other buffer (flies during compute)
        if (s + 1 < S) {
            int bj = bj0 + ((s + 1) >> 1), h = (s + 1) & 1;
            const unsigned char* gB =
                zn8 + (size_t)(bj * 128 + h * 64 + rowL) * DDIM + chunk * 16;
            unsigned char* lB = sB[(s + 1) & 1] + t * 16;
            #pragma unroll
            for (int q = 0; q < 4; q++)
                load_lds16(gB + q * 4096, lB + q * 4096);
        }

        if (s == 0) {      // one-time A-frag read from LDS into registers
            #pragma unroll
            for (int mt = 0; mt < 4; mt++)
                #pragma unroll
                for (int ks = 0; ks < 2; ks++) {
                    int g0 = ks * 8 + quad * 2;
                    i32x4 lo = *(const i32x4*)(aRow + mt * 16 * DDIM + ((g0    ) ^ col) * 16);
                    i32x4 hi = *(const i32x4*)(aRow + mt * 16 * DDIM + ((g0 + 1) ^ col) * 16);
                    af[mt][ks] = __builtin_shufflevector(lo, hi, 0, 1, 2, 3, 4, 5, 6, 7);
                }
        }

        // ---- compute stage s ----
        int bj = bj0 + (s >> 1), h = s & 1;
        int jBase = bj * 128;
        bool isDiag = (bj == bi);
        const unsigned char* bRow = sB[s & 1] + (size_t)(wn * 32 + col) * DDIM;

        i32x8 bfr[2][2];
        #pragma unroll
        for (int nt = 0; nt < 2; nt++)
            #pragma unroll
            for (int ks = 0; ks < 2; ks++) {
                int g0 = ks * 8 + quad * 2;
                i32x4 lo = *(const i32x4*)(bRow + nt * 16 * DDIM + ((g0    ) ^ col) * 16);
                i32x4 hi = *(const i32x4*)(bRow + nt * 16 * DDIM + ((g0 + 1) ^ col) * 16);
                bfr[nt][ks] = __builtin_shufflevector(lo, hi, 0, 1, 2, 3, 4, 5, 6, 7);
            }

        float cs[2] = {0.f, 0.f};
        #pragma unroll
        for (int mt = 0; mt < 4; mt++) {
            int gi = iBase + wm * 64 + mt * 16;
            #pragma unroll
            for (int nt = 0; nt < 2; nt++) {
                f32x4 acc = {0.f, 0.f, 0.f, 0.f};
                acc = __builtin_amdgcn_mfma_scale_f32_16x16x128_f8f6f4(
                          af[mt][0], bfr[nt][0], acc, 0, 0, 0, SCALE1, 0, SCALE1);
                acc = __builtin_amdgcn_mfma_scale_f32_16x16x128_f8f6f4(
                          af[mt][1], bfr[nt][1], acc, 0, 0, 0, SCALE1, 0, SCALE1);
                bool dtile = (gi == jBase + h * 64 + wn * 32 + nt * 16);
                float csl = 0.f;
                #pragma unroll
                for (int r = 0; r < 4; r++) {
                    float e = exp2f(acc[r] * TWO_LOG2E);
                    if (dtile && (quad * 4 + r) == col) e = 0.f;
                    rs[mt][r] += e;
                    csl += e;
                }
                cs[nt] += csl;
            }
        }

        // col-sums for this stage (off-diag tiles only)
        if (!isDiag) {
            #pragma unroll
            for (int nt = 0; nt < 2; nt++) {
                float v = cs[nt];
                v += __shfl_xor(v, 16);
                v += __shfl_xor(v, 32);
                if (quad == 0)
                    atomicAdd(&denom[jBase + h * 64 + wn * 32 + nt * 16 + col], v);
            }
        }
    }

    // ---- epilogue (once per block): row-sum reduce + combine + 128 atomics ----
    #pragma unroll
    for (int mt = 0; mt < 4; mt++)
        #pragma unroll
        for (int r = 0; r < 4; r++) {
            float v = rs[mt][r];
            v += __shfl_xor(v, 1);
            v += __shfl_xor(v, 2);
            v += __shfl_xor(v, 4);
            v += __shfl_xor(v, 8);
            rs[mt][r] = v;
        }
    __syncthreads();                     // all compute done; sA reusable
    float* red = (float*)sA;
    if (col == 0) {
        #pragma unroll
        for (int mt = 0; mt < 4; mt++)
            #pragma unroll
            for (int r = 0; r < 4; r++)
                red[wn * 128 + wm * 64 + mt * 16 + quad * 4 + r] = rs[mt][r];
    }
    __syncthreads();
    if (t < 128)
        atomicAdd(&denom[iBase + t], red[t] + red[128 + t]);
}

// Kernel 3: final reduction, 32 blocks, atomic into prep-zeroed out[0].
__global__ __launch_bounds__(256) void loss_kernel(const float* __restrict__ posPart,
                                                   const float* __restrict__ denom,
                                                   float* __restrict__ out) {
    __shared__ float sdata[4];
    int t = threadIdx.x;
    float s = __logf(denom[blockIdx.x * 256 + t]);
    if (t < 32) s -= 2.0f * posPart[blockIdx.x * 32 + t];
    #pragma unroll
    for (int off = 32; off; off >>= 1) s += __shfl_xor(s, off);
    if ((t & 63) == 0) sdata[t >> 6] = s;
    __syncthreads();
    if (t == 0)
        atomicAdd(out, (sdata[0] + sdata[1] + sdata[2] + sdata[3]) * (1.0f / NROWS));
}

extern "C" void kernel_launch(void* const* d_in, const int* in_sizes, int n_in,
                              void* d_out, int out_size, void* d_ws, size_t ws_size,
                              hipStream_t stream) {
    const float* z1 = (const float*)d_in[0];
    const float* z2 = (const float*)d_in[1];

    // ws: zn8 fp8 [8192*256] (2 MB) | denom f32[8192] | posPart f32[1024]
    unsigned char* zn8 = (unsigned char*)d_ws;
    float* denom   = (float*)((char*)d_ws + (size_t)NROWS * DDIM);
    float* posPart = denom + NROWS;

    prep_kernel<<<BHALF / 4, 256, 0, stream>>>(z1, z2, zn8, posPart, denom, (float*)d_out);
    denom_kernel<<<dim3(16, 64), 256, 0, stream>>>(zn8, denom);
    loss_kernel<<<NROWS / 256, 256, 0, stream>>>(posPart, denom, (float*)d_out);
}

// Round 12
// 86.312 us; speedup vs baseline: 1.1372x; 1.1372x over previous
//
#include <hip/hip_runtime.h>
#include <hip/hip_bf16.h>

// SimCLR NT-Xent loss. B=4096, D=256, N=2B=8192 rows.
// loss = (1/N) sum_i [ log(denom_i) - log(pos_i) ]
//   denom_i = sum_{j!=i} exp(2*sim_ij),  pos_i = cos(z_i, z_{i+-B}) (fp32 path)
//
// R12 = R10 (best: 87.2 us; triangular 128x128 fp8 scaled-MFMA, 48 KB LDS,
// 3 blocks/CU, 2080 one-tile blocks) + two surgical cuts inside the tile:
//  (a) A-fragments read into registers ONCE (R10 re-read per half),
//  (b) A's LDS space reused as the B-half-1 buffer, with the B1 prefetch
//      issued BEFORE half-0 compute (drain overlapped; degrades to exactly
//      R10 if the compiler sinks it — unlike R11, which changed the block
//      schedule and regressed).
// R11 lesson: 544-block/2-per-CU schedule lost ~11 us to residency
// quantization + TLP loss; pipeline must ride inside R10's schedule.

#define NROWS 8192
#define BHALF 4096
#define DDIM  256

typedef __attribute__((ext_vector_type(4))) int   i32x4;
typedef __attribute__((ext_vector_type(8))) int   i32x8;
typedef __attribute__((ext_vector_type(4))) float f32x4;

#define SCALE1 0x7F7F7F7F               // e8m0 biased-127 = 2^0 in every byte
#define TWO_LOG2E 2.8853900817779268f   // 2/ln(2): exp(2x) = exp2(x*TWO_LOG2E)

__device__ __forceinline__ void load_lds16(const unsigned char* g, unsigned char* l) {
    __builtin_amdgcn_global_load_lds(
        (const __attribute__((address_space(1))) void*)g,
        (__attribute__((address_space(3))) void*)l, 16, 0, 0);
}

// Kernel 1: norms + fp8-normalized matrix + positive-pair log partials +
// denom zero-init + out zero-init. (unchanged, verified)
__global__ __launch_bounds__(256) void prep_kernel(const float* __restrict__ z1,
                                                   const float* __restrict__ z2,
                                                   unsigned char* __restrict__ zn8,
                                                   float* __restrict__ posPart,
                                                   float* __restrict__ denom,
                                                   float* __restrict__ out) {
    __shared__ float sp[4];
    int wave = threadIdx.x >> 6;
    int lane = threadIdx.x & 63;
    int i    = blockIdx.x * 4 + wave;
    float4 a = reinterpret_cast<const float4*>(z1 + (size_t)i * DDIM)[lane];
    float4 b = reinterpret_cast<const float4*>(z2 + (size_t)i * DDIM)[lane];
    float ss1 = a.x * a.x + a.y * a.y + a.z * a.z + a.w * a.w;
    float ss2 = b.x * b.x + b.y * b.y + b.z * b.z + b.w * b.w;
    float dd  = a.x * b.x + a.y * b.y + a.z * b.z + a.w * b.w;
    #pragma unroll
    for (int off = 32; off; off >>= 1) {
        ss1 += __shfl_xor(ss1, off);
        ss2 += __shfl_xor(ss2, off);
        dd  += __shfl_xor(dd, off);
    }
    float n1 = fmaxf(sqrtf(ss1), 1e-8f);
    float n2 = fmaxf(sqrtf(ss2), 1e-8f);
    float i1 = 1.0f / n1, i2 = 1.0f / n2;
    int pa = __builtin_amdgcn_cvt_pk_fp8_f32(a.x * i1, a.y * i1, 0, 0);
    pa     = __builtin_amdgcn_cvt_pk_fp8_f32(a.z * i1, a.w * i1, pa, 1);
    int pb = __builtin_amdgcn_cvt_pk_fp8_f32(b.x * i2, b.y * i2, 0, 0);
    pb     = __builtin_amdgcn_cvt_pk_fp8_f32(b.z * i2, b.w * i2, pb, 1);
    reinterpret_cast<int*>(zn8 + (size_t)i * DDIM)[lane] = pa;
    reinterpret_cast<int*>(zn8 + (size_t)(i + BHALF) * DDIM)[lane] = pb;
    if (lane == 0) sp[wave] = __logf(dd * i1 * i2);
    if (threadIdx.x < 8) denom[blockIdx.x * 8 + threadIdx.x] = 0.0f;
    if (blockIdx.x == 0 && threadIdx.x == 64) out[0] = 0.0f;
    __syncthreads();
    if (threadIdx.x == 0)
        posPart[blockIdx.x] = sp[0] + sp[1] + sp[2] + sp[3];
}

// Kernel 2: fp8 MFMA sim-GEMM + exp row/col-sums, upper-triangular 128x128
// tiles. LDS 48 KB: A(32 KB, consumed to regs) aliased by B1(16 KB) + B0(16 KB).
__global__ __launch_bounds__(256, 3) void denom_kernel(const unsigned char* __restrict__ zn8,
                                                       float* __restrict__ denom) {
    __shared__ __align__(16) unsigned char sMem[48 * 1024];
    unsigned char* sA  = sMem;            // 32 KB, read into regs then dead
    unsigned char* sB0 = sMem + 32768;    // 16 KB
    unsigned char* sB1 = sMem;            // aliases A's first 16 KB

    // triangular decode: 65x32 grid -> {(bi,bj) : 0 <= bi <= bj < 64}
    int x = blockIdx.x, y = blockIdx.y;
    int bi, bj;
    if (x > y) { bi = y;      bj = x - 1;  }
    else       { bi = 63 - y; bj = 63 - x; }
    int iBase = bi * 128;
    int jBase = bj * 128;
    bool isDiag = (bi == bj);

    int t    = threadIdx.x;
    int lane = t & 63;
    int wave = t >> 6;
    int col  = lane & 15;
    int quad = lane >> 4;
    int wm = wave >> 1, wn = wave & 1;

    // staging addresses (granule id = q*256 + t; row = q*16 + rowL;
    // slot pos (t&15) holds k-chunk (t&15)^rowL — verified XOR swizzle)
    int rowL  = t >> 4;
    int chunk = (t & 15) ^ rowL;

    // ---- stage A (128 rows) + B half 0 (64 rows) ----
    {
        const unsigned char* gA = zn8 + (size_t)(iBase + rowL) * DDIM + chunk * 16;
        #pragma unroll
        for (int q = 0; q < 8; q++)
            load_lds16(gA + q * 4096, sA + t * 16 + q * 4096);
        const unsigned char* gB = zn8 + (size_t)(jBase + rowL) * DDIM + chunk * 16;
        #pragma unroll
        for (int q = 0; q < 4; q++)
            load_lds16(gB + q * 4096, sB0 + t * 16 + q * 4096);
    }
    __syncthreads();

    // ---- A-fragments -> registers (once per tile) ----
    i32x8 af[4][2];
    {
        const unsigned char* aRow = sA + (size_t)(wm * 64 + col) * DDIM;
        #pragma unroll
        for (int mt = 0; mt < 4; mt++)
            #pragma unroll
            for (int ks = 0; ks < 2; ks++) {
                int g0 = ks * 8 + quad * 2;
                i32x4 lo = *(const i32x4*)(aRow + mt * 16 * DDIM + ((g0    ) ^ col) * 16);
                i32x4 hi = *(const i32x4*)(aRow + mt * 16 * DDIM + ((g0 + 1) ^ col) * 16);
                af[mt][ks] = __builtin_shufflevector(lo, hi, 0, 1, 2, 3, 4, 5, 6, 7);
            }
    }
    __syncthreads();   // all waves done with sA (lgkm-only drain: cheap)

    // ---- prefetch B half 1 into sB1 (flies during half-0 compute) ----
    {
        const unsigned char* gB = zn8 + (size_t)(jBase + 64 + rowL) * DDIM + chunk * 16;
        #pragma unroll
        for (int q = 0; q < 4; q++)
            load_lds16(gB + q * 4096, sB1 + t * 16 + q * 4096);
    }

    float rs[4][4];                     // row-sums, accumulated over both halves
    #pragma unroll
    for (int mt = 0; mt < 4; mt++)
        #pragma unroll
        for (int r = 0; r < 4; r++) rs[mt][r] = 0.f;

    #pragma unroll
    for (int h = 0; h < 2; h++) {
        if (h) __syncthreads();          // drains B1 (issued one compute phase ago)
        const unsigned char* bRow =
            (h ? sB1 : sB0) + (size_t)(wn * 32 + col) * DDIM;

        // B fragments: row' = wn*32 + nt*16 + col (row'&15 == col)
        i32x8 bfr[2][2];
        #pragma unroll
        for (int nt = 0; nt < 2; nt++)
            #pragma unroll
            for (int ks = 0; ks < 2; ks++) {
                int g0 = ks * 8 + quad * 2;
                i32x4 lo = *(const i32x4*)(bRow + nt * 16 * DDIM + ((g0    ) ^ col) * 16);
                i32x4 hi = *(const i32x4*)(bRow + nt * 16 * DDIM + ((g0 + 1) ^ col) * 16);
                bfr[nt][ks] = __builtin_shufflevector(lo, hi, 0, 1, 2, 3, 4, 5, 6, 7);
            }

        float cs[2] = {0.f, 0.f};
        #pragma unroll
        for (int mt = 0; mt < 4; mt++) {
            int gi = iBase + wm * 64 + mt * 16;
            #pragma unroll
            for (int nt = 0; nt < 2; nt++) {
                f32x4 acc = {0.f, 0.f, 0.f, 0.f};
                acc = __builtin_amdgcn_mfma_scale_f32_16x16x128_f8f6f4(
                          af[mt][0], bfr[nt][0], acc, 0, 0, 0, SCALE1, 0, SCALE1);
                acc = __builtin_amdgcn_mfma_scale_f32_16x16x128_f8f6f4(
                          af[mt][1], bfr[nt][1], acc, 0, 0, 0, SCALE1, 0, SCALE1);
                bool dtile = (gi == jBase + h * 64 + wn * 32 + nt * 16);
                float csl = 0.f;
                #pragma unroll
                for (int r = 0; r < 4; r++) {
                    float e = exp2f(acc[r] * TWO_LOG2E);
                    if (dtile && (quad * 4 + r) == col) e = 0.f;
                    rs[mt][r] += e;
                    csl += e;
                }
                cs[nt] += csl;
            }
        }

        // col-sums for this half (off-diag tiles only)
        if (!isDiag) {
            #pragma unroll
            for (int nt = 0; nt < 2; nt++) {
                float v = cs[nt];
                v += __shfl_xor(v, 16);
                v += __shfl_xor(v, 32);
                if (quad == 0)
                    atomicAdd(&denom[jBase + h * 64 + wn * 32 + nt * 16 + col], v);
            }
        }
    }

    // ---- row-sums: reduce 16 col-lanes, combine wn pair via LDS, 128 atomics ----
    #pragma unroll
    for (int mt = 0; mt < 4; mt++)
        #pragma unroll
        for (int r = 0; r < 4; r++) {
            float v = rs[mt][r];
            v += __shfl_xor(v, 1);
            v += __shfl_xor(v, 2);
            v += __shfl_xor(v, 4);
            v += __shfl_xor(v, 8);
            rs[mt][r] = v;
        }
    __syncthreads();                     // all compute reads done
    float* red = (float*)(sMem + 16384); // scratch region, no live aliasing
    if (col == 0) {
        #pragma unroll
        for (int mt = 0; mt < 4; mt++)
            #pragma unroll
            for (int r = 0; r < 4; r++)
                red[wn * 128 + wm * 64 + mt * 16 + quad * 4 + r] = rs[mt][r];
    }
    __syncthreads();
    if (t < 128)
        atomicAdd(&denom[iBase + t], red[t] + red[128 + t]);
}

// Kernel 3: final reduction, 32 blocks, atomic into prep-zeroed out[0].
__global__ __launch_bounds__(256) void loss_kernel(const float* __restrict__ posPart,
                                                   const float* __restrict__ denom,
                                                   float* __restrict__ out) {
    __shared__ float sdata[4];
    int t = threadIdx.x;
    float s = __logf(denom[blockIdx.x * 256 + t]);
    if (t < 32) s -= 2.0f * posPart[blockIdx.x * 32 + t];
    #pragma unroll
    for (int off = 32; off; off >>= 1) s += __shfl_xor(s, off);
    if ((t & 63) == 0) sdata[t >> 6] = s;
    __syncthreads();
    if (t == 0)
        atomicAdd(out, (sdata[0] + sdata[1] + sdata[2] + sdata[3]) * (1.0f / NROWS));
}

extern "C" void kernel_launch(void* const* d_in, const int* in_sizes, int n_in,
                              void* d_out, int out_size, void* d_ws, size_t ws_size,
                              hipStream_t stream) {
    const float* z1 = (const float*)d_in[0];
    const float* z2 = (const float*)d_in[1];

    // ws: zn8 fp8 [8192*256] (2 MB) | denom f32[8192] | posPart f32[1024]
    unsigned char* zn8 = (unsigned char*)d_ws;
    float* denom   = (float*)((char*)d_ws + (size_t)NROWS * DDIM);
    float* posPart = denom + NROWS;

    prep_kernel<<<BHALF / 4, 256, 0, stream>>>(z1, z2, zn8, posPart, denom, (float*)d_out);
    denom_kernel<<<dim3(65, 32), 256, 0, stream>>>(zn8, denom);
    loss_kernel<<<NROWS / 256, 256, 0, stream>>>(posPart, denom, (float*)d_out);
}